// Round 3
// baseline (459.303 us; speedup 1.0000x reference)
//
#include <hip/hip_runtime.h>

// o_x[r,c] = l_xx*X[r,c] + g_xx*sumX[r] + g_yx*sumY[r]
// o_y[r,c] = l_yy*Y[r,c] + g_yy*sumY[r] + g_xy*sumX[r]
// R=8192 rows, N=4096 cols.
//
// Barrier-free design: ONE WAVE PER ROW. Phase A streams the row from HBM
// accumulating sums (wave-internal shfl_xor reduce -> no LDS, no
// __syncthreads). Phase B re-reads the row (L1/L2/L3 hit - touched ~1us ago,
// per-CU in-flight working set ~1MB << 4MiB L2/XCD) and writes outputs with
// nontemporal stores. Waves never wait on each other; read & write streams
// from different waves mix in the memory pipe.

constexpr int N_COLS = 4096;
constexpr int V4_PER_LANE = N_COLS / 4 / 64;   // 16 float4 per lane per row

typedef float v4f __attribute__((ext_vector_type(4)));

__global__ __launch_bounds__(256, 4) void pequinn_waverow(
    const float* __restrict__ X, const float* __restrict__ Y,
    const float* __restrict__ p_lxx, const float* __restrict__ p_lyy,
    const float* __restrict__ p_gxx, const float* __restrict__ p_gxy,
    const float* __restrict__ p_gyx, const float* __restrict__ p_gyy,
    float* __restrict__ o_x, float* __restrict__ o_y)
{
    const int wave = threadIdx.x >> 6;               // 0..3
    const int lane = threadIdx.x & 63;
    const int row  = blockIdx.x * 4 + wave;          // one wave per row
    const size_t base = (size_t)row * N_COLS;

    const v4f* Xr = (const v4f*)(X + base);
    const v4f* Yr = (const v4f*)(Y + base);

    // ---- Phase A: stream row, accumulate sums (data discarded) ----
    float sx = 0.f, sy = 0.f;
#pragma unroll
    for (int i = 0; i < V4_PER_LANE; ++i) {
        const v4f x = Xr[lane + 64 * i];
        sx += (x.x + x.y) + (x.z + x.w);
    }
#pragma unroll
    for (int i = 0; i < V4_PER_LANE; ++i) {
        const v4f y = Yr[lane + 64 * i];
        sy += (y.x + y.y) + (y.z + y.w);
    }

    // Wave-64 butterfly (xor) reduce: every lane ends with the full row sum.
#pragma unroll
    for (int off = 1; off < 64; off <<= 1) {
        sx += __shfl_xor(sx, off, 64);
        sy += __shfl_xor(sy, off, 64);
    }

    // Scalar params (uniform loads, L2-resident).
    const float lxx = p_lxx[0], lyy = p_lyy[0];
    const float gxx = p_gxx[0], gxy = p_gxy[0];
    const float gyx = p_gyx[0], gyy = p_gyy[0];

    const float bx = gxx * sx + gyx * sy;   // row-constant term for o_x
    const float by = gyy * sy + gxy * sx;   // row-constant term for o_y

    // ---- Phase B: re-read row (cache hit) and write outputs ----
    v4f* Ox = (v4f*)(o_x + base);
    v4f* Oy = (v4f*)(o_y + base);
#pragma unroll
    for (int i = 0; i < V4_PER_LANE; ++i) {
        const v4f x = Xr[lane + 64 * i];
        v4f ox;
        ox.x = fmaf(lxx, x.x, bx);
        ox.y = fmaf(lxx, x.y, bx);
        ox.z = fmaf(lxx, x.z, bx);
        ox.w = fmaf(lxx, x.w, bx);
        __builtin_nontemporal_store(ox, Ox + lane + 64 * i);
    }
#pragma unroll
    for (int i = 0; i < V4_PER_LANE; ++i) {
        const v4f y = Yr[lane + 64 * i];
        v4f oy;
        oy.x = fmaf(lyy, y.x, by);
        oy.y = fmaf(lyy, y.y, by);
        oy.z = fmaf(lyy, y.z, by);
        oy.w = fmaf(lyy, y.w, by);
        __builtin_nontemporal_store(oy, Oy + lane + 64 * i);
    }
}

extern "C" void kernel_launch(void* const* d_in, const int* in_sizes, int n_in,
                              void* d_out, int out_size, void* d_ws, size_t ws_size,
                              hipStream_t stream) {
    const float* X    = (const float*)d_in[0];
    const float* Y    = (const float*)d_in[1];
    const float* lxx  = (const float*)d_in[2];
    const float* lyy  = (const float*)d_in[3];
    const float* gxx  = (const float*)d_in[4];
    const float* gxy  = (const float*)d_in[5];
    const float* gyx  = (const float*)d_in[6];
    const float* gyy  = (const float*)d_in[7];

    const int R = in_sizes[0] / N_COLS;     // 8192
    float* o_x = (float*)d_out;                       // first output, R*N floats
    float* o_y = (float*)d_out + (size_t)R * N_COLS;  // second output

    // 4 waves (rows) per 256-thread block.
    pequinn_waverow<<<R / 4, 256, 0, stream>>>(X, Y, lxx, lyy, gxx, gxy, gyx, gyy,
                                               o_x, o_y);
}